// Round 4
// baseline (201.949 us; speedup 1.0000x reference)
//
#include <hip/hip_runtime.h>

// ---------------------------------------------------------------------------
// MNIST Langevin Encoder — round 4:
//   * copy_kernel = pure branch-free nontemporal grid-stride memcpy
//   * scatter of winner rows folded into langevin (runs after copy)
//   * winner zeroing touches only the 16384 idx entries (no 4MB fill)
// Pipeline: zero_touched -> prep -> gemm1 -> gemm2 -> winner -> copy ->
//           langevin(+scatter)
// ---------------------------------------------------------------------------

#define ZD 64
#define NSTEPS 25
#define EPSI 0.01f
#define K1 784
#define K1P 800
#define HSTR 512   // padded hidden stride (bf16 h)

typedef __attribute__((ext_vector_type(8))) short short8;
typedef __attribute__((ext_vector_type(4))) float f32x4;

__device__ __forceinline__ unsigned short f2bf(float f) {
  union { float f; unsigned u; } v; v.f = f;
  return (unsigned short)((v.u + 0x7FFFu + ((v.u >> 16) & 1u)) >> 16);
}

__device__ __forceinline__ void gload_lds16(const void* g, void* l) {
  __builtin_amdgcn_global_load_lds(
      (const __attribute__((address_space(1))) void*)g,
      (__attribute__((address_space(3))) void*)l, 16, 0, 0);
}

// ---------------- prep: W1 -> w1b[512][800] bf16 ; [W21;W22] -> wout[128][512]
__global__ __launch_bounds__(256) void prep_kernel(
    const float* __restrict__ W1, const float* __restrict__ W21,
    const float* __restrict__ W22, short* __restrict__ W1b,
    short* __restrict__ Wout) {
  const int t = blockIdx.x * 256 + threadIdx.x;
  const int NW1 = 512 * (K1P / 8);   // 51200 chunks of 8
  if (t < NW1) {
    const int n = t / (K1P / 8), k0 = (t % (K1P / 8)) * 8;
    short8 v = {0, 0, 0, 0, 0, 0, 0, 0};
    if (n < 400 && k0 < K1) {
      const float* s = W1 + (long)n * K1 + k0;
#pragma unroll
      for (int e = 0; e < 8; e++) v[e] = (short)f2bf(s[e]);
    }
    *(short8*)(W1b + (long)t * 8) = v;
  } else {
    const int q = t - NW1;           // wout: 128*64 = 8192 chunks
    if (q < 128 * 64) {
      const int n = q / 64, k0 = (q % 64) * 8;
      short8 v = {0, 0, 0, 0, 0, 0, 0, 0};
      if (k0 < 400) {
        const float* s = (n < 64) ? (W21 + (long)n * 400 + k0)
                                  : (W22 + (long)(n - 64) * 400 + k0);
#pragma unroll
        for (int e = 0; e < 8; e++) v[e] = (short)f2bf(s[e]);
      }
      *(short8*)(Wout + (long)q * 8) = v;
    }
  }
}

// ---------------- zero only the winner entries we will read ----------------
__global__ __launch_bounds__(256) void zero_touched_kernel(
    const int* __restrict__ idx, int* __restrict__ winner, int B) {
  const int j = blockIdx.x * 256 + threadIdx.x;
  if (j < B) winner[idx[j]] = 0;     // races benign: all write 0
}

// ---------------- winner: last duplicate index wins ------------------------
__global__ __launch_bounds__(256) void winner_kernel(
    const int* __restrict__ idx, int* __restrict__ winner, int B) {
  const int j = blockIdx.x * 256 + threadIdx.x;
  if (j < B) atomicMax(&winner[idx[j]], j + 1);
}

// ---------------- GEMM1: h = relu(X @ W1^T + b1), bf16 MFMA ----------------
// BM=64, BN=512 (full), BK=32, 512 threads = 8 waves (2x4), wave tile 32x128.
__global__ __launch_bounds__(512) void gemm1_kernel(
    const float* __restrict__ X, const short* __restrict__ W1b,
    const float* __restrict__ b1, unsigned short* __restrict__ H) {
  __shared__ short As[4 * 64 * 8];    // 4 KB, frag-major
  __shared__ short Bs[32 * 64 * 8];   // 32 KB, frag-major
  const int tid = threadIdx.x;
  const int w = tid >> 6;
  const int lane = tid & 63;
  const int wr = w >> 2;   // 0..1
  const int wc = w & 3;    // 0..3
  const int m0 = blockIdx.x * 64;

  const f32x4 vzero = {0.f, 0.f, 0.f, 0.f};
  f32x4 acc[2][8];
#pragma unroll
  for (int i = 0; i < 2; i++)
#pragma unroll
    for (int j = 0; j < 8; j++) acc[i][j] = vzero;

  for (int k0 = 0; k0 < K1P; k0 += 32) {
    if (k0) __syncthreads();
    // A tile (64x32): reg-stage from fp32 x with on-the-fly cvt (tid<256).
    if (tid < 256) {
      const int row = m0 + (tid >> 6) * 16 + (lane & 15);
      const int gk = k0 + (lane >> 4) * 8;
      short8 av = {0, 0, 0, 0, 0, 0, 0, 0};
      if (gk < K1) {
        const float4 f0 = *(const float4*)(X + (long)row * K1 + gk);
        const float4 f1 = *(const float4*)(X + (long)row * K1 + gk + 4);
        av[0] = (short)f2bf(f0.x); av[1] = (short)f2bf(f0.y);
        av[2] = (short)f2bf(f0.z); av[3] = (short)f2bf(f0.w);
        av[4] = (short)f2bf(f1.x); av[5] = (short)f2bf(f1.y);
        av[6] = (short)f2bf(f1.z); av[7] = (short)f2bf(f1.w);
      }
      *(short8*)(As + (long)tid * 8) = av;
    }
    // B tile (512x32): global_load_lds, 4 groups per wave.
#pragma unroll
    for (int t = 0; t < 4; t++) {
      const int gn = w * 4 + t;
      const short* src = W1b + (long)(gn * 16 + (lane & 15)) * K1P +
                         k0 + (lane >> 4) * 8;
      gload_lds16(src, Bs + gn * 512);
    }
    __syncthreads();
    const short8* Ap = (const short8*)As;
    const short8* Bp = (const short8*)Bs;
    const short8 a0 = Ap[(wr * 2 + 0) * 64 + lane];
    const short8 a1 = Ap[(wr * 2 + 1) * 64 + lane];
#pragma unroll
    for (int j = 0; j < 8; j++) {
      const short8 b = Bp[(wc * 8 + j) * 64 + lane];
      acc[0][j] = __builtin_amdgcn_mfma_f32_16x16x32_bf16(a0, b, acc[0][j], 0, 0, 0);
      acc[1][j] = __builtin_amdgcn_mfma_f32_16x16x32_bf16(a1, b, acc[1][j], 0, 0, 0);
    }
  }
  // epilogue: bias + relu + cvt -> bf16 h[row][col], stride 512
  const int colg = lane & 15;
  const int rowg = (lane >> 4) * 4;
#pragma unroll
  for (int j = 0; j < 8; j++) {
    const int col = wc * 128 + j * 16 + colg;
    const float bias = (col < 400) ? b1[col] : 0.f;
#pragma unroll
    for (int i = 0; i < 2; i++) {
      const int rbase = m0 + wr * 32 + i * 16 + rowg;
#pragma unroll
      for (int r = 0; r < 4; r++) {
        H[(long)(rbase + r) * HSTR + col] = f2bf(fmaxf(acc[i][j][r] + bias, 0.f));
      }
    }
  }
}

// ---------------- GEMM2: [zloc|u] = h @ Wout^T + b, bf16 MFMA --------------
// BM=64, BN=128 (full), BK=32, 256 threads = 4 waves (2x2), wave tile 32x64.
__global__ __launch_bounds__(256) void gemm2_kernel(
    const unsigned short* __restrict__ H, const short* __restrict__ Wout,
    const float* __restrict__ b21, const float* __restrict__ b22,
    float* __restrict__ zloc, float* __restrict__ uarr) {
  __shared__ short As[4 * 64 * 8];   // 4 KB
  __shared__ short Bs[8 * 64 * 8];   // 8 KB
  const int tid = threadIdx.x;
  const int w = tid >> 6;
  const int lane = tid & 63;
  const int wr = w >> 1;   // 0..1
  const int wc = w & 1;    // 0..1
  const int m0 = blockIdx.x * 64;

  const f32x4 vzero = {0.f, 0.f, 0.f, 0.f};
  f32x4 acc[2][4];
#pragma unroll
  for (int i = 0; i < 2; i++)
#pragma unroll
    for (int j = 0; j < 4; j++) acc[i][j] = vzero;

  for (int k0 = 0; k0 < HSTR; k0 += 32) {
    if (k0) __syncthreads();
    {  // A group g = w
      const unsigned short* src = H + (long)(m0 + w * 16 + (lane & 15)) * HSTR +
                                  k0 + (lane >> 4) * 8;
      gload_lds16(src, As + w * 512);
    }
#pragma unroll
    for (int t = 0; t < 2; t++) {  // B groups
      const int gn = w * 2 + t;
      const short* src = Wout + (long)(gn * 16 + (lane & 15)) * HSTR +
                         k0 + (lane >> 4) * 8;
      gload_lds16(src, Bs + gn * 512);
    }
    __syncthreads();
    const short8* Ap = (const short8*)As;
    const short8* Bp = (const short8*)Bs;
    const short8 a0 = Ap[(wr * 2 + 0) * 64 + lane];
    const short8 a1 = Ap[(wr * 2 + 1) * 64 + lane];
#pragma unroll
    for (int j = 0; j < 4; j++) {
      const short8 b = Bp[(wc * 4 + j) * 64 + lane];
      acc[0][j] = __builtin_amdgcn_mfma_f32_16x16x32_bf16(a0, b, acc[0][j], 0, 0, 0);
      acc[1][j] = __builtin_amdgcn_mfma_f32_16x16x32_bf16(a1, b, acc[1][j], 0, 0, 0);
    }
  }
  const int colg = lane & 15;
  const int rowg = (lane >> 4) * 4;
  float* outp = wc ? uarr : zloc;
  const float* bp = wc ? b22 : b21;
#pragma unroll
  for (int j = 0; j < 4; j++) {
    const int col = j * 16 + colg;     // 0..63 within zloc or u
    const float bias = bp[col];
#pragma unroll
    for (int i = 0; i < 2; i++) {
      const int rbase = m0 + wr * 32 + i * 16 + rowg;
#pragma unroll
      for (int r = 0; r < 4; r++) {
        outp[(long)(rbase + r) * ZD + col] = acc[i][j][r] + bias;
      }
    }
  }
}

// ---------------- pure streaming copy: out_cache = cache -------------------
// grid-stride, 2048 blocks x 256 thr, 32 float4/thread, nontemporal.
#define COPY_BLOCKS 2048
__global__ __launch_bounds__(256) void copy_kernel(
    const f32x4* __restrict__ src, f32x4* __restrict__ dst, long n4) {
  const long base = (long)blockIdx.x * 256 * 32 + threadIdx.x;
#pragma unroll
  for (int k = 0; k < 32; k++) {
    const long e = base + (long)k * 256;
    if (e < n4) {
      f32x4 v = __builtin_nontemporal_load(&src[e]);
      __builtin_nontemporal_store(v, &dst[e]);
    }
  }
}

// ---------------- Langevin + logq + winner-row scatter ---------------------
// grid-stride: 2048 blocks x 4 row-slots, 2 iterations covers B=16384.
__global__ __launch_bounds__(256) void langevin_kernel(
    const float* __restrict__ zloc, const float* __restrict__ uarr,
    const float* __restrict__ cache, const int* __restrict__ idx,
    const float* __restrict__ noise, const int* __restrict__ winner,
    float* __restrict__ out_logq, float* __restrict__ out_z,
    float* __restrict__ out_cache, int B) {
  const int lane = threadIdx.x & 63;
  const int slot = blockIdx.x * 4 + (threadIdx.x >> 6);
  const int nslots = gridDim.x * 4;
  const float coef = sqrtf(2.f * EPSI);
  const long stride = (long)B * ZD;
  for (int row = slot; row < B; row += nslots) {
    const int i = idx[row];
    const float zl = zloc[(long)row * ZD + lane];
    const float uu = uarr[(long)row * ZD + lane];
    const float a = EPSI * expf(-2.f * uu);  // EPS * inv_var
    float z = cache[(long)i * ZD + lane];
    const float* np = noise + (long)row * ZD + lane;
#pragma unroll
    for (int s = 0; s < NSTEPS; s++) {
      z = z + a * (zl - z) + coef * np[(long)s * stride];
    }
    out_z[(long)row * ZD + lane] = z;
    // scatter into new cache if this row is the last writer of index i
    if (winner[i] == row + 1) {
      out_cache[(long)i * ZD + lane] = z;
    }
    const float d = (z - zl) * expf(-uu);
    float t = -0.5f * d * d - uu - 0.91893853320467274178f;
#pragma unroll
    for (int off = 1; off < 64; off <<= 1) t += __shfl_xor(t, off);
    if (lane == 0) out_logq[row] = t;
  }
}

extern "C" void kernel_launch(void* const* d_in, const int* in_sizes, int n_in,
                              void* d_out, int out_size, void* d_ws, size_t ws_size,
                              hipStream_t stream) {
  const float* x     = (const float*)d_in[0];
  const int*   idx   = (const int*)d_in[1];
  const float* W1    = (const float*)d_in[3];
  const float* b1    = (const float*)d_in[4];
  const float* W21   = (const float*)d_in[5];
  const float* b21   = (const float*)d_in[6];
  const float* W22   = (const float*)d_in[7];
  const float* b22   = (const float*)d_in[8];
  const float* cache = (const float*)d_in[9];
  const float* noise = (const float*)d_in[10];

  const int B  = in_sizes[1];            // 16384
  const int DS = in_sizes[9] / ZD;       // 1000000

  float* out_logq  = (float*)d_out;
  float* out_z     = out_logq + B;
  float* out_cache = out_z + (long)B * ZD;

  // workspace layout (~30.1 MB)
  unsigned short* h = (unsigned short*)d_ws;              // B*512 bf16
  short* w1b  = (short*)(h + (long)B * HSTR);             // 512*800 bf16
  short* wout = w1b + 512 * K1P;                          // 128*512 bf16
  float* zloc = (float*)(wout + 128 * HSTR);              // B*64 f32
  float* u    = zloc + (long)B * ZD;                      // B*64 f32
  int*   win  = (int*)(u + (long)B * ZD);                 // DS ints

  zero_touched_kernel<<<(B + 255) / 256, 256, 0, stream>>>(idx, win, B);

  const int prep_chunks = 512 * (K1P / 8) + 128 * 64;
  prep_kernel<<<(prep_chunks + 255) / 256, 256, 0, stream>>>(W1, W21, W22, w1b, wout);
  gemm1_kernel<<<B / 64, 512, 0, stream>>>(x, w1b, b1, h);
  gemm2_kernel<<<B / 64, 256, 0, stream>>>(h, wout, b21, b22, zloc, u);
  winner_kernel<<<(B + 255) / 256, 256, 0, stream>>>(idx, win, B);

  const long total4 = (long)DS * (ZD / 4);                // 16M float4
  copy_kernel<<<COPY_BLOCKS, 256, 0, stream>>>(
      (const f32x4*)cache, (f32x4*)out_cache, total4);

  langevin_kernel<<<2048, 256, 0, stream>>>(zloc, u, cache, idx, noise, win,
                                            out_logq, out_z, out_cache, B);
}

// Round 5
// 191.888 us; speedup vs baseline: 1.0524x; 1.0524x over previous
//
#include <hip/hip_runtime.h>

// ---------------------------------------------------------------------------
// MNIST Langevin Encoder — round 5: revert to r3 copy/langevin structure
// (r4's restructure regressed 14us); single change vs r3: BM 64->32 in both
// GEMMs for 4 blocks/CU occupancy (was 1/CU -> barrier stalls unhidden).
//   h      = relu(x @ W1^T + b1)           (16384 x 400), bf16, padded [..][512]
//   [z_loc | u] = h @ [W21;W22]^T + [b21;b22]   (16384 x 128) fp32
//   z0     = cache[idx]; 25 ULA steps; logq; new_cache scatter-copy.
// ---------------------------------------------------------------------------

#define ZD 64
#define NSTEPS 25
#define EPSI 0.01f
#define K1 784
#define K1P 800
#define HSTR 512   // padded hidden stride (bf16 h)

typedef __attribute__((ext_vector_type(8))) short short8;
typedef __attribute__((ext_vector_type(4))) float f32x4;
typedef __attribute__((ext_vector_type(4))) int i32x4;

__device__ __forceinline__ unsigned short f2bf(float f) {
  union { float f; unsigned u; } v; v.f = f;
  return (unsigned short)((v.u + 0x7FFFu + ((v.u >> 16) & 1u)) >> 16);
}

__device__ __forceinline__ void gload_lds16(const void* g, void* l) {
  __builtin_amdgcn_global_load_lds(
      (const __attribute__((address_space(1))) void*)g,
      (__attribute__((address_space(3))) void*)l, 16, 0, 0);
}

// ---------------- prep: W1 -> w1b[512][800] bf16 ; [W21;W22] -> wout[128][512]
__global__ __launch_bounds__(256) void prep_kernel(
    const float* __restrict__ W1, const float* __restrict__ W21,
    const float* __restrict__ W22, short* __restrict__ W1b,
    short* __restrict__ Wout) {
  const int t = blockIdx.x * 256 + threadIdx.x;
  const int NW1 = 512 * (K1P / 8);   // 51200 chunks of 8
  if (t < NW1) {
    const int n = t / (K1P / 8), k0 = (t % (K1P / 8)) * 8;
    short8 v = {0, 0, 0, 0, 0, 0, 0, 0};
    if (n < 400 && k0 < K1) {
      const float* s = W1 + (long)n * K1 + k0;
#pragma unroll
      for (int e = 0; e < 8; e++) v[e] = (short)f2bf(s[e]);
    }
    *(short8*)(W1b + (long)t * 8) = v;
  } else {
    const int q = t - NW1;           // wout: 128*64 = 8192 chunks
    if (q < 128 * 64) {
      const int n = q / 64, k0 = (q % 64) * 8;
      short8 v = {0, 0, 0, 0, 0, 0, 0, 0};
      if (k0 < 400) {
        const float* s = (n < 64) ? (W21 + (long)n * 400 + k0)
                                  : (W22 + (long)(n - 64) * 400 + k0);
#pragma unroll
        for (int e = 0; e < 8; e++) v[e] = (short)f2bf(s[e]);
      }
      *(short8*)(Wout + (long)q * 8) = v;
    }
  }
}

// ---------------- zero winner array ----------------------------------------
__global__ __launch_bounds__(256) void zero_win_kernel(i32x4* __restrict__ win4, int n4) {
  const int t = blockIdx.x * 256 + threadIdx.x;
  if (t < n4) win4[t] = (i32x4){0, 0, 0, 0};
}

// ---------------- winner: last duplicate index wins ------------------------
__global__ __launch_bounds__(256) void winner_kernel(
    const int* __restrict__ idx, int* __restrict__ winner, int B) {
  const int j = blockIdx.x * 256 + threadIdx.x;
  if (j < B) atomicMax(&winner[idx[j]], j + 1);
}

// ---------------- GEMM1: h = relu(X @ W1^T + b1), bf16 MFMA ----------------
// BM=32, BN=512 (full), BK=32, 256 threads = 4 waves, wave tile 32x128.
// LDS 34KB -> 4 blocks/CU.
__global__ __launch_bounds__(256) void gemm1_kernel(
    const float* __restrict__ X, const short* __restrict__ W1b,
    const float* __restrict__ b1, unsigned short* __restrict__ H) {
  __shared__ short As[2 * 64 * 8];    // 2 KB, frag-major (2 row groups)
  __shared__ short Bs[32 * 64 * 8];   // 32 KB, frag-major (32 col groups)
  const int tid = threadIdx.x;
  const int w = tid >> 6;
  const int lane = tid & 63;
  const int m0 = blockIdx.x * 32;

  const f32x4 vzero = {0.f, 0.f, 0.f, 0.f};
  f32x4 acc[2][8];
#pragma unroll
  for (int i = 0; i < 2; i++)
#pragma unroll
    for (int j = 0; j < 8; j++) acc[i][j] = vzero;

  for (int k0 = 0; k0 < K1P; k0 += 32) {
    if (k0) __syncthreads();
    // A tile (32x32): reg-stage from fp32 x with on-the-fly cvt (tid<128).
    if (tid < 128) {
      const int row = m0 + (tid >> 6) * 16 + (lane & 15);
      const int gk = k0 + (lane >> 4) * 8;
      short8 av = {0, 0, 0, 0, 0, 0, 0, 0};
      if (gk < K1) {
        const float4 f0 = *(const float4*)(X + (long)row * K1 + gk);
        const float4 f1 = *(const float4*)(X + (long)row * K1 + gk + 4);
        av[0] = (short)f2bf(f0.x); av[1] = (short)f2bf(f0.y);
        av[2] = (short)f2bf(f0.z); av[3] = (short)f2bf(f0.w);
        av[4] = (short)f2bf(f1.x); av[5] = (short)f2bf(f1.y);
        av[6] = (short)f2bf(f1.z); av[7] = (short)f2bf(f1.w);
      }
      *(short8*)(As + (long)tid * 8) = av;
    }
    // B tile (512x32): global_load_lds, 8 groups per wave.
#pragma unroll
    for (int t = 0; t < 8; t++) {
      const int gn = w * 8 + t;
      const short* src = W1b + (long)(gn * 16 + (lane & 15)) * K1P +
                         k0 + (lane >> 4) * 8;
      gload_lds16(src, Bs + gn * 512);
    }
    __syncthreads();
    const short8* Ap = (const short8*)As;
    const short8* Bp = (const short8*)Bs;
    const short8 a0 = Ap[0 * 64 + lane];
    const short8 a1 = Ap[1 * 64 + lane];
#pragma unroll
    for (int j = 0; j < 8; j++) {
      const short8 b = Bp[(w * 8 + j) * 64 + lane];
      acc[0][j] = __builtin_amdgcn_mfma_f32_16x16x32_bf16(a0, b, acc[0][j], 0, 0, 0);
      acc[1][j] = __builtin_amdgcn_mfma_f32_16x16x32_bf16(a1, b, acc[1][j], 0, 0, 0);
    }
  }
  // epilogue: bias + relu + cvt -> bf16 h[row][col], stride 512
  const int colg = lane & 15;
  const int rowg = (lane >> 4) * 4;
#pragma unroll
  for (int j = 0; j < 8; j++) {
    const int col = w * 128 + j * 16 + colg;
    const float bias = (col < 400) ? b1[col] : 0.f;
#pragma unroll
    for (int i = 0; i < 2; i++) {
      const int rbase = m0 + i * 16 + rowg;
#pragma unroll
      for (int r = 0; r < 4; r++) {
        H[(long)(rbase + r) * HSTR + col] = f2bf(fmaxf(acc[i][j][r] + bias, 0.f));
      }
    }
  }
}

// ---------------- GEMM2: [zloc|u] = h @ Wout^T + b, bf16 MFMA --------------
// BM=32, BN=128 (full), BK=32, 256 threads = 4 waves, wave tile 32x32.
__global__ __launch_bounds__(256) void gemm2_kernel(
    const unsigned short* __restrict__ H, const short* __restrict__ Wout,
    const float* __restrict__ b21, const float* __restrict__ b22,
    float* __restrict__ zloc, float* __restrict__ uarr) {
  __shared__ short As[2 * 64 * 8];   // 2 KB
  __shared__ short Bs[8 * 64 * 8];   // 8 KB
  const int tid = threadIdx.x;
  const int w = tid >> 6;
  const int lane = tid & 63;
  const int m0 = blockIdx.x * 32;

  const f32x4 vzero = {0.f, 0.f, 0.f, 0.f};
  f32x4 acc[2][2];
#pragma unroll
  for (int i = 0; i < 2; i++)
#pragma unroll
    for (int j = 0; j < 2; j++) acc[i][j] = vzero;

  for (int k0 = 0; k0 < HSTR; k0 += 32) {
    if (k0) __syncthreads();
    if (w < 2) {  // A groups 0..1 via waves 0..1
      const unsigned short* src = H + (long)(m0 + w * 16 + (lane & 15)) * HSTR +
                                  k0 + (lane >> 4) * 8;
      gload_lds16(src, As + w * 512);
    }
#pragma unroll
    for (int t = 0; t < 2; t++) {  // B groups, 2 per wave
      const int gn = w * 2 + t;
      const short* src = Wout + (long)(gn * 16 + (lane & 15)) * HSTR +
                         k0 + (lane >> 4) * 8;
      gload_lds16(src, Bs + gn * 512);
    }
    __syncthreads();
    const short8* Ap = (const short8*)As;
    const short8* Bp = (const short8*)Bs;
    const short8 a0 = Ap[0 * 64 + lane];
    const short8 a1 = Ap[1 * 64 + lane];
#pragma unroll
    for (int j = 0; j < 2; j++) {
      const short8 b = Bp[(w * 2 + j) * 64 + lane];
      acc[0][j] = __builtin_amdgcn_mfma_f32_16x16x32_bf16(a0, b, acc[0][j], 0, 0, 0);
      acc[1][j] = __builtin_amdgcn_mfma_f32_16x16x32_bf16(a1, b, acc[1][j], 0, 0, 0);
    }
  }
  const int colg = lane & 15;
  const int rowg = (lane >> 4) * 4;
  float* outp = (w < 2) ? zloc : uarr;
  const float* bp = (w < 2) ? b21 : b22;
#pragma unroll
  for (int j = 0; j < 2; j++) {
    const int col = (w & 1) * 32 + j * 16 + colg;   // 0..63 within zloc or u
    const float bias = bp[col];
#pragma unroll
    for (int i = 0; i < 2; i++) {
      const int rbase = m0 + i * 16 + rowg;
#pragma unroll
      for (int r = 0; r < 4; r++) {
        outp[(long)(rbase + r) * ZD + col] = acc[i][j][r] + bias;
      }
    }
  }
}

// ---------------- Langevin + logq (r3 structure) ---------------------------
__global__ __launch_bounds__(256) void langevin_kernel(
    const float* __restrict__ zloc, const float* __restrict__ uarr,
    const float* __restrict__ cache, const int* __restrict__ idx,
    const float* __restrict__ noise, float* __restrict__ out_logq,
    float* __restrict__ out_z, int B) {
  const int row = blockIdx.x * 4 + (threadIdx.x >> 6);
  const int lane = threadIdx.x & 63;
  const int i = idx[row];
  const float zl = zloc[(long)row * ZD + lane];
  const float uu = uarr[(long)row * ZD + lane];
  const float a = EPSI * expf(-2.f * uu);  // EPS * inv_var
  float z = cache[(long)i * ZD + lane];
  const float coef = sqrtf(2.f * EPSI);
  const float* np = noise + (long)row * ZD + lane;
  const long stride = (long)B * ZD;
#pragma unroll
  for (int s = 0; s < NSTEPS; s++) {
    z = z + a * (zl - z) + coef * np[(long)s * stride];
  }
  out_z[(long)row * ZD + lane] = z;
  const float d = (z - zl) * expf(-uu);
  float t = -0.5f * d * d - uu - 0.91893853320467274178f;
#pragma unroll
  for (int off = 1; off < 64; off <<= 1) t += __shfl_xor(t, off);
  if (lane == 0) out_logq[row] = t;
}

// ---------------- cache copy + scatter (r3 structure, nontemporal) ---------
__global__ __launch_bounds__(256) void copy_kernel(
    const f32x4* __restrict__ cache4, const f32x4* __restrict__ z4,
    const int* __restrict__ winner, f32x4* __restrict__ out4) {
  const long e = (long)blockIdx.x * 256 + threadIdx.x;  // element = row*16 + c
  const long row = e >> 4;
  const int c = (int)(e & 15);
  const int w = winner[row];
  f32x4 v;
  if (w == 0) v = __builtin_nontemporal_load(&cache4[e]);
  else        v = z4[(long)(w - 1) * 16 + c];
  __builtin_nontemporal_store(v, &out4[e]);
}

extern "C" void kernel_launch(void* const* d_in, const int* in_sizes, int n_in,
                              void* d_out, int out_size, void* d_ws, size_t ws_size,
                              hipStream_t stream) {
  const float* x     = (const float*)d_in[0];
  const int*   idx   = (const int*)d_in[1];
  const float* W1    = (const float*)d_in[3];
  const float* b1    = (const float*)d_in[4];
  const float* W21   = (const float*)d_in[5];
  const float* b21   = (const float*)d_in[6];
  const float* W22   = (const float*)d_in[7];
  const float* b22   = (const float*)d_in[8];
  const float* cache = (const float*)d_in[9];
  const float* noise = (const float*)d_in[10];

  const int B  = in_sizes[1];            // 16384
  const int DS = in_sizes[9] / ZD;       // 1000000

  float* out_logq  = (float*)d_out;
  float* out_z     = out_logq + B;
  float* out_cache = out_z + (long)B * ZD;

  // workspace layout (~30.1 MB)
  unsigned short* h = (unsigned short*)d_ws;              // B*512 bf16
  short* w1b  = (short*)(h + (long)B * HSTR);             // 512*800 bf16
  short* wout = w1b + 512 * K1P;                          // 128*512 bf16
  float* zloc = (float*)(wout + 128 * HSTR);              // B*64 f32
  float* u    = zloc + (long)B * ZD;                      // B*64 f32
  int*   win  = (int*)(u + (long)B * ZD);                 // DS ints

  const int n4 = (DS + 3) / 4;                            // 250000 int4
  zero_win_kernel<<<(n4 + 255) / 256, 256, 0, stream>>>((i32x4*)win, n4);

  const int prep_chunks = 512 * (K1P / 8) + 128 * 64;
  prep_kernel<<<(prep_chunks + 255) / 256, 256, 0, stream>>>(W1, W21, W22, w1b, wout);
  gemm1_kernel<<<B / 32, 256, 0, stream>>>(x, w1b, b1, h);
  gemm2_kernel<<<B / 32, 256, 0, stream>>>(h, wout, b21, b22, zloc, u);
  winner_kernel<<<(B + 255) / 256, 256, 0, stream>>>(idx, win, B);
  langevin_kernel<<<B / 4, 256, 0, stream>>>(zloc, u, cache, idx, noise,
                                             out_logq, out_z, B);
  const long total4 = (long)DS * (ZD / 4);
  copy_kernel<<<(unsigned)(total4 / 256), 256, 0, stream>>>(
      (const f32x4*)cache, (const f32x4*)out_z, win, (f32x4*)out_cache);
}

// Round 7
// 191.153 us; speedup vs baseline: 1.0565x; 1.0038x over previous
//
#include <hip/hip_runtime.h>

// ---------------------------------------------------------------------------
// MNIST Langevin Encoder — round 7: fix r6's dependency bug. The copy role
// fused into gemm1 is now a PURE stream out_cache = cache (no winner/z deps);
// winner rows are overwritten later by langevin's scatter (r4 semantics,
// proven correct). Pipeline: zero_win -> prep -> winner -> [gemm1+copy] ->
// gemm2 -> langevin(+scatter).
// ---------------------------------------------------------------------------

#define ZD 64
#define NSTEPS 25
#define EPSI 0.01f
#define K1 784
#define K1P 800
#define HSTR 512   // padded hidden stride (bf16 h)
#define COPYB 2048 // copy blocks fused into gemm1 dispatch

typedef __attribute__((ext_vector_type(8))) short short8;
typedef __attribute__((ext_vector_type(4))) float f32x4;
typedef __attribute__((ext_vector_type(4))) int i32x4;

__device__ __forceinline__ unsigned short f2bf(float f) {
  union { float f; unsigned u; } v; v.f = f;
  return (unsigned short)((v.u + 0x7FFFu + ((v.u >> 16) & 1u)) >> 16);
}

__device__ __forceinline__ void gload_lds16(const void* g, void* l) {
  __builtin_amdgcn_global_load_lds(
      (const __attribute__((address_space(1))) void*)g,
      (__attribute__((address_space(3))) void*)l, 16, 0, 0);
}

// ---------------- prep: W1 -> w1b[512][800] bf16 ; [W21;W22] -> wout[128][512]
__global__ __launch_bounds__(256) void prep_kernel(
    const float* __restrict__ W1, const float* __restrict__ W21,
    const float* __restrict__ W22, short* __restrict__ W1b,
    short* __restrict__ Wout) {
  const int t = blockIdx.x * 256 + threadIdx.x;
  const int NW1 = 512 * (K1P / 8);   // 51200 chunks of 8
  if (t < NW1) {
    const int n = t / (K1P / 8), k0 = (t % (K1P / 8)) * 8;
    short8 v = {0, 0, 0, 0, 0, 0, 0, 0};
    if (n < 400 && k0 < K1) {
      const float* s = W1 + (long)n * K1 + k0;
#pragma unroll
      for (int e = 0; e < 8; e++) v[e] = (short)f2bf(s[e]);
    }
    *(short8*)(W1b + (long)t * 8) = v;
  } else {
    const int q = t - NW1;           // wout: 128*64 = 8192 chunks
    if (q < 128 * 64) {
      const int n = q / 64, k0 = (q % 64) * 8;
      short8 v = {0, 0, 0, 0, 0, 0, 0, 0};
      if (k0 < 400) {
        const float* s = (n < 64) ? (W21 + (long)n * 400 + k0)
                                  : (W22 + (long)(n - 64) * 400 + k0);
#pragma unroll
        for (int e = 0; e < 8; e++) v[e] = (short)f2bf(s[e]);
      }
      *(short8*)(Wout + (long)q * 8) = v;
    }
  }
}

// ---------------- zero winner array ----------------------------------------
__global__ __launch_bounds__(256) void zero_win_kernel(i32x4* __restrict__ win4, int n4) {
  const int t = blockIdx.x * 256 + threadIdx.x;
  if (t < n4) win4[t] = (i32x4){0, 0, 0, 0};
}

// ---------------- winner: last duplicate index wins ------------------------
__global__ __launch_bounds__(256) void winner_kernel(
    const int* __restrict__ idx, int* __restrict__ winner, int B) {
  const int j = blockIdx.x * 256 + threadIdx.x;
  if (j < B) atomicMax(&winner[idx[j]], j + 1);
}

// ---------------- fused GEMM1 + PURE cache copy ----------------------------
// blocks [0, ngemm): h = relu(X @ W1^T + b1)  (BM=32, BN=512, BK=32, 4 waves)
// blocks [ngemm, ngemm+COPYB): out_cache = cache (pure stream, no deps)
__global__ __launch_bounds__(256) void gemm1_copy_kernel(
    const float* __restrict__ X, const short* __restrict__ W1b,
    const float* __restrict__ b1, unsigned short* __restrict__ H,
    const f32x4* __restrict__ cache4, f32x4* __restrict__ out4,
    int ngemm, long n4) {
  __shared__ short As[2 * 64 * 8];    // 2 KB, frag-major (2 row groups)
  __shared__ short Bs[32 * 64 * 8];   // 32 KB, frag-major (32 col groups)
  const int tid = threadIdx.x;

  if ((int)blockIdx.x >= ngemm) {
    // ---------- copy role: pure branch-free stream ----------
    const long base = (long)(blockIdx.x - ngemm) * (256 * 32) + tid;
#pragma unroll
    for (int k = 0; k < 32; k++) {
      const long e = base + (long)k * 256;
      if (e < n4) {
        f32x4 v = __builtin_nontemporal_load(&cache4[e]);
        __builtin_nontemporal_store(v, &out4[e]);
      }
    }
    return;
  }

  // ---------- gemm role (r5 body) ----------
  const int w = tid >> 6;
  const int lane = tid & 63;
  const int m0 = blockIdx.x * 32;

  const f32x4 vzero = {0.f, 0.f, 0.f, 0.f};
  f32x4 acc[2][8];
#pragma unroll
  for (int i = 0; i < 2; i++)
#pragma unroll
    for (int j = 0; j < 8; j++) acc[i][j] = vzero;

  for (int k0 = 0; k0 < K1P; k0 += 32) {
    if (k0) __syncthreads();
    // A tile (32x32): reg-stage from fp32 x with on-the-fly cvt (tid<128).
    if (tid < 128) {
      const int row = m0 + (tid >> 6) * 16 + (lane & 15);
      const int gk = k0 + (lane >> 4) * 8;
      short8 av = {0, 0, 0, 0, 0, 0, 0, 0};
      if (gk < K1) {
        const float4 f0 = *(const float4*)(X + (long)row * K1 + gk);
        const float4 f1 = *(const float4*)(X + (long)row * K1 + gk + 4);
        av[0] = (short)f2bf(f0.x); av[1] = (short)f2bf(f0.y);
        av[2] = (short)f2bf(f0.z); av[3] = (short)f2bf(f0.w);
        av[4] = (short)f2bf(f1.x); av[5] = (short)f2bf(f1.y);
        av[6] = (short)f2bf(f1.z); av[7] = (short)f2bf(f1.w);
      }
      *(short8*)(As + (long)tid * 8) = av;
    }
    // B tile (512x32): global_load_lds, 8 groups per wave.
#pragma unroll
    for (int t = 0; t < 8; t++) {
      const int gn = w * 8 + t;
      const short* src = W1b + (long)(gn * 16 + (lane & 15)) * K1P +
                         k0 + (lane >> 4) * 8;
      gload_lds16(src, Bs + gn * 512);
    }
    __syncthreads();
    const short8* Ap = (const short8*)As;
    const short8* Bp = (const short8*)Bs;
    const short8 a0 = Ap[0 * 64 + lane];
    const short8 a1 = Ap[1 * 64 + lane];
#pragma unroll
    for (int j = 0; j < 8; j++) {
      const short8 b = Bp[(w * 8 + j) * 64 + lane];
      acc[0][j] = __builtin_amdgcn_mfma_f32_16x16x32_bf16(a0, b, acc[0][j], 0, 0, 0);
      acc[1][j] = __builtin_amdgcn_mfma_f32_16x16x32_bf16(a1, b, acc[1][j], 0, 0, 0);
    }
  }
  // epilogue: bias + relu + cvt -> bf16 h[row][col], stride 512
  const int colg = lane & 15;
  const int rowg = (lane >> 4) * 4;
#pragma unroll
  for (int j = 0; j < 8; j++) {
    const int col = w * 128 + j * 16 + colg;
    const float bias = (col < 400) ? b1[col] : 0.f;
#pragma unroll
    for (int i = 0; i < 2; i++) {
      const int rbase = m0 + i * 16 + rowg;
#pragma unroll
      for (int r = 0; r < 4; r++) {
        H[(long)(rbase + r) * HSTR + col] = f2bf(fmaxf(acc[i][j][r] + bias, 0.f));
      }
    }
  }
}

// ---------------- GEMM2: [zloc|u] = h @ Wout^T + b, bf16 MFMA --------------
// BM=32, BN=128 (full), BK=32, 256 threads = 4 waves, wave tile 32x32.
__global__ __launch_bounds__(256) void gemm2_kernel(
    const unsigned short* __restrict__ H, const short* __restrict__ Wout,
    const float* __restrict__ b21, const float* __restrict__ b22,
    float* __restrict__ zloc, float* __restrict__ uarr) {
  __shared__ short As[2 * 64 * 8];   // 2 KB
  __shared__ short Bs[8 * 64 * 8];   // 8 KB
  const int tid = threadIdx.x;
  const int w = tid >> 6;
  const int lane = tid & 63;
  const int m0 = blockIdx.x * 32;

  const f32x4 vzero = {0.f, 0.f, 0.f, 0.f};
  f32x4 acc[2][2];
#pragma unroll
  for (int i = 0; i < 2; i++)
#pragma unroll
    for (int j = 0; j < 2; j++) acc[i][j] = vzero;

  for (int k0 = 0; k0 < HSTR; k0 += 32) {
    if (k0) __syncthreads();
    if (w < 2) {  // A groups 0..1 via waves 0..1
      const unsigned short* src = H + (long)(m0 + w * 16 + (lane & 15)) * HSTR +
                                  k0 + (lane >> 4) * 8;
      gload_lds16(src, As + w * 512);
    }
#pragma unroll
    for (int t = 0; t < 2; t++) {  // B groups, 2 per wave
      const int gn = w * 2 + t;
      const short* src = Wout + (long)(gn * 16 + (lane & 15)) * HSTR +
                         k0 + (lane >> 4) * 8;
      gload_lds16(src, Bs + gn * 512);
    }
    __syncthreads();
    const short8* Ap = (const short8*)As;
    const short8* Bp = (const short8*)Bs;
    const short8 a0 = Ap[0 * 64 + lane];
    const short8 a1 = Ap[1 * 64 + lane];
#pragma unroll
    for (int j = 0; j < 2; j++) {
      const short8 b = Bp[(w * 2 + j) * 64 + lane];
      acc[0][j] = __builtin_amdgcn_mfma_f32_16x16x32_bf16(a0, b, acc[0][j], 0, 0, 0);
      acc[1][j] = __builtin_amdgcn_mfma_f32_16x16x32_bf16(a1, b, acc[1][j], 0, 0, 0);
    }
  }
  const int colg = lane & 15;
  const int rowg = (lane >> 4) * 4;
  float* outp = (w < 2) ? zloc : uarr;
  const float* bp = (w < 2) ? b21 : b22;
#pragma unroll
  for (int j = 0; j < 2; j++) {
    const int col = (w & 1) * 32 + j * 16 + colg;   // 0..63 within zloc or u
    const float bias = bp[col];
#pragma unroll
    for (int i = 0; i < 2; i++) {
      const int rbase = m0 + i * 16 + rowg;
#pragma unroll
      for (int r = 0; r < 4; r++) {
        outp[(long)(rbase + r) * ZD + col] = acc[i][j][r] + bias;
      }
    }
  }
}

// ---------------- Langevin + logq + winner-row scatter ---------------------
__global__ __launch_bounds__(256) void langevin_kernel(
    const float* __restrict__ zloc, const float* __restrict__ uarr,
    const float* __restrict__ cache, const int* __restrict__ idx,
    const float* __restrict__ noise, const int* __restrict__ winner,
    float* __restrict__ out_logq, float* __restrict__ out_z,
    float* __restrict__ out_cache, int B) {
  const int row = blockIdx.x * 4 + (threadIdx.x >> 6);
  const int lane = threadIdx.x & 63;
  const int i = idx[row];
  const float zl = zloc[(long)row * ZD + lane];
  const float uu = uarr[(long)row * ZD + lane];
  const float a = EPSI * expf(-2.f * uu);  // EPS * inv_var
  float z = cache[(long)i * ZD + lane];
  const float coef = sqrtf(2.f * EPSI);
  const float* np = noise + (long)row * ZD + lane;
  const long stride = (long)B * ZD;
#pragma unroll
  for (int s = 0; s < NSTEPS; s++) {
    z = z + a * (zl - z) + coef * np[(long)s * stride];
  }
  out_z[(long)row * ZD + lane] = z;
  // overwrite winner rows in new cache (copy already wrote cache there)
  if (winner[i] == row + 1) {
    out_cache[(long)i * ZD + lane] = z;
  }
  const float d = (z - zl) * expf(-uu);
  float t = -0.5f * d * d - uu - 0.91893853320467274178f;
#pragma unroll
  for (int off = 1; off < 64; off <<= 1) t += __shfl_xor(t, off);
  if (lane == 0) out_logq[row] = t;
}

extern "C" void kernel_launch(void* const* d_in, const int* in_sizes, int n_in,
                              void* d_out, int out_size, void* d_ws, size_t ws_size,
                              hipStream_t stream) {
  const float* x     = (const float*)d_in[0];
  const int*   idx   = (const int*)d_in[1];
  const float* W1    = (const float*)d_in[3];
  const float* b1    = (const float*)d_in[4];
  const float* W21   = (const float*)d_in[5];
  const float* b21   = (const float*)d_in[6];
  const float* W22   = (const float*)d_in[7];
  const float* b22   = (const float*)d_in[8];
  const float* cache = (const float*)d_in[9];
  const float* noise = (const float*)d_in[10];

  const int B  = in_sizes[1];            // 16384
  const int DS = in_sizes[9] / ZD;       // 1000000

  float* out_logq  = (float*)d_out;
  float* out_z     = out_logq + B;
  float* out_cache = out_z + (long)B * ZD;

  // workspace layout (~30.1 MB)
  unsigned short* h = (unsigned short*)d_ws;              // B*512 bf16
  short* w1b  = (short*)(h + (long)B * HSTR);             // 512*800 bf16
  short* wout = w1b + 512 * K1P;                          // 128*512 bf16
  float* zloc = (float*)(wout + 128 * HSTR);              // B*64 f32
  float* u    = zloc + (long)B * ZD;                      // B*64 f32
  int*   win  = (int*)(u + (long)B * ZD);                 // DS ints

  const int n4i = (DS + 3) / 4;                           // 250000 int4
  zero_win_kernel<<<(n4i + 255) / 256, 256, 0, stream>>>((i32x4*)win, n4i);

  const int prep_chunks = 512 * (K1P / 8) + 128 * 64;
  prep_kernel<<<(prep_chunks + 255) / 256, 256, 0, stream>>>(W1, W21, W22, w1b, wout);
  winner_kernel<<<(B + 255) / 256, 256, 0, stream>>>(idx, win, B);

  const int ngemm = B / 32;                               // 512 gemm blocks
  const long total4 = (long)DS * (ZD / 4);                // 16M float4
  gemm1_copy_kernel<<<ngemm + COPYB, 256, 0, stream>>>(
      x, w1b, b1, h, (const f32x4*)cache, (f32x4*)out_cache, ngemm, total4);

  gemm2_kernel<<<B / 32, 256, 0, stream>>>(h, wout, b21, b22, zloc, u);
  langevin_kernel<<<B / 4, 256, 0, stream>>>(zloc, u, cache, idx, noise, win,
                                             out_logq, out_z, out_cache, B);
}